// Round 9
// baseline (216.632 us; speedup 1.0000x reference)
//
#include <hip/hip_runtime.h>
#include <hip/hip_fp16.h>

#define N_NODES 100000
#define E_EDGES 1600000
#define IN_C 128
#define HID_C 64
#define OUT_C 32
#define CAP 64                                      // padded per-node slots (P(deg>=64)~1e-19)

// ---- zero the per-node degree counters (workspace is poisoned between iterations) ----
__global__ void zero_ncur_kernel(int* __restrict__ ncur) {
    int i = blockIdx.x * 256 + threadIdx.x;
    if (i < N_NODES) ncur[i] = 0;
}

// ---- direct padded scatter: col[dst*64 + slot] = src, slot by global atomic.
//      Replaces the whole bucket hist/reserve/sort chain: intra-node order is
//      nondeterministic, but so was the bucket-window order since round 1 —
//      absmax has been bit-stable (fp16-dominated) across 8 rounds of orders. ----
__global__ __launch_bounds__(256) void edge_scatter_kernel(const int* __restrict__ src,
                                                           const int* __restrict__ dst,
                                                           int* __restrict__ ncur,
                                                           int* __restrict__ colp) {
    int i = blockIdx.x * 256 + threadIdx.x;        // grid 6250*256 == E exactly
    int d = dst[i];
    int s = src[i];
    int pos = atomicAdd(&ncur[d], 1);
    if (pos < CAP) colp[(d << 6) + pos] = s;       // guard: memory safety only
}

// ---- hs(fp16) = dinv[row] * (x @ W1) : 2 rows x 8 cols per thread, 64 rows/block,
//      grid 1563 (round-7 occupancy fix). dinv computed inline from ncur
//      (rsqrtf of identical float input -> bit-identical). ----
__global__ __launch_bounds__(256) void gemm1_kernel(const float* __restrict__ x,
                                                    const float* __restrict__ W1,
                                                    const int* __restrict__ ncur,
                                                    __half* __restrict__ hs) {
    __shared__ float sW[IN_C * HID_C];
    for (int i = threadIdx.x; i < IN_C * HID_C; i += 256) sW[i] = W1[i];
    __syncthreads();
    const int cg = (threadIdx.x & 7) * 8;
    const int row0 = blockIdx.x * 64 + (threadIdx.x >> 3) * 2;
    float acc[2][8];
#pragma unroll
    for (int r = 0; r < 2; ++r)
#pragma unroll
        for (int c = 0; c < 8; ++c) acc[r][c] = 0.f;

    int rr[2];
#pragma unroll
    for (int r = 0; r < 2; ++r) rr[r] = min(row0 + r, N_NODES - 1);

    const float4* x4 = (const float4*)x;
#pragma unroll 2
    for (int k4 = 0; k4 < IN_C / 4; ++k4) {
        float4 xv[2];
#pragma unroll
        for (int r = 0; r < 2; ++r) xv[r] = x4[(size_t)rr[r] * (IN_C / 4) + k4];
        float xs[2][4];
#pragma unroll
        for (int r = 0; r < 2; ++r) {
            xs[r][0] = xv[r].x; xs[r][1] = xv[r].y; xs[r][2] = xv[r].z; xs[r][3] = xv[r].w;
        }
#pragma unroll
        for (int kk = 0; kk < 4; ++kk) {
            const float4* wp = (const float4*)(sW + (k4 * 4 + kk) * HID_C + cg);
            float4 w0 = wp[0], w1 = wp[1];
            float wv[8] = {w0.x, w0.y, w0.z, w0.w, w1.x, w1.y, w1.z, w1.w};
#pragma unroll
            for (int r = 0; r < 2; ++r)
#pragma unroll
                for (int c = 0; c < 8; ++c)
                    acc[r][c] = fmaf(xs[r][kk], wv[c], acc[r][c]);
        }
    }
#pragma unroll
    for (int r = 0; r < 2; ++r) {
        int row = row0 + r;
        if (row < N_NODES) {
            float dv = rsqrtf((float)ncur[row] + 1.0f);
            union { float4 f; __half2 h[4]; } u;
#pragma unroll
            for (int q = 0; q < 4; ++q)
                u.h[q] = __floats2half2_rn(acc[r][2 * q] * dv, acc[r][2 * q + 1] * dv);
            *(float4*)(hs + (size_t)row * HID_C + cg) = u.f;   // 16 B packed store
        }
    }
}

// ---- layer-1 aggregate + FUSED gemm2 (round-4 proven form, 42.2 us):
//      16 lanes x float2 per node (4 nodes/wave), full 128 B rows; col coalesced
//      by 8 lanes + __shfl broadcast + next-chunk col prefetch. Epilogue: h2 row
//      staged in 2 KB LDS tile; gemm2 vs 8 KB LDS W2 copy, k ascending ->
//      bit-identical gs. Rows now at col[node*64 .. +cnt) (padded CSR).
//      gs must NOT alias hs. ----
__global__ __launch_bounds__(256) void agg1_kernel(const int* __restrict__ ncur,
                                                   const int* __restrict__ col,
                                                   const float2* __restrict__ hsf,
                                                   const float* __restrict__ b1,
                                                   const float* __restrict__ W2,
                                                   __half* __restrict__ gs) {
    __shared__ float sW[HID_C * OUT_C];            // 8 KB W2 copy
    __shared__ __half2 sh2[16][HID_C / 2];         // 2 KB h2 tile (16 nodes x 64 ch)
    for (int i = threadIdx.x; i < HID_C * OUT_C; i += 256) sW[i] = W2[i];

    const int nl = threadIdx.x >> 4;               // node slot in block (0..15)
    const int node = blockIdx.x * 16 + nl;         // grid 6250 * 16 = exactly N
    const int lane = threadIdx.x & 15;             // float2 index: channels 4*lane..4*lane+3
    const int cnt = min(ncur[node], CAP);
    const int beg = node << 6;                     // padded row base
    const int end = beg + cnt;
    float2 u = hsf[(size_t)node * 16 + lane];      // self loop
    __half2* uh = (__half2*)&u;
    float2 t0 = __half22float2(uh[0]), t1 = __half22float2(uh[1]);
    float a0 = t0.x, a1 = t0.y, a2 = t1.x, a3 = t1.y;

    int j = beg;
    int idx0 = j + (lane & 7);
    int cv = (idx0 < end) ? col[idx0] : 0;         // current chunk's indices (coalesced)
    while (j + 8 <= end) {
        int jn = j + 8;
        int idxn = jn + (lane & 7);
        int cvn = (idxn < end) ? col[idxn] : 0;    // prefetch next chunk
        int s[8];
#pragma unroll
        for (int e = 0; e < 8; ++e) s[e] = __shfl(cv, e, 8);
        float2 v[8];
#pragma unroll
        for (int e = 0; e < 8; ++e) v[e] = hsf[(size_t)s[e] * 16 + lane];
        cv = cvn;
#pragma unroll
        for (int e = 0; e < 8; ++e) {
            __half2* vh = (__half2*)&v[e];
            float2 w0 = __half22float2(vh[0]), w1 = __half22float2(vh[1]);
            a0 += w0.x; a1 += w0.y; a2 += w1.x; a3 += w1.y;
        }
        j = jn;
    }
    const int tail = end - j;                      // 0..7, cv already holds tail indices
    for (int e = 0; e < tail; ++e) {
        int s = __shfl(cv, e, 8);
        float2 v = hsf[(size_t)s * 16 + lane];
        __half2* vh = (__half2*)&v;
        float2 w0 = __half22float2(vh[0]), w1 = __half22float2(vh[1]);
        a0 += w0.x; a1 += w0.y; a2 += w1.x; a3 += w1.y;
    }
    const float dv = rsqrtf((float)cnt + 1.0f);
    float4 bb = ((const float4*)b1)[lane];
    __half2 p0 = __floats2half2_rn(fmaxf(dv * a0 + bb.x, 0.f), fmaxf(dv * a1 + bb.y, 0.f));
    __half2 p1 = __floats2half2_rn(fmaxf(dv * a2 + bb.z, 0.f), fmaxf(dv * a3 + bb.w, 0.f));
    sh2[nl][lane * 2] = p0;
    sh2[nl][lane * 2 + 1] = p1;
    __syncthreads();                               // covers sW and sh2

    // gemm2 phase: thread -> (node nl, out channels oc, oc+1); k order 0..63 sequential
    const int oc = lane * 2;
    float o0 = 0.f, o1 = 0.f;
#pragma unroll
    for (int k2 = 0; k2 < HID_C / 2; ++k2) {
        float2 hv = __half22float2(sh2[nl][k2]);
        const float* w0 = sW + (2 * k2) * OUT_C + oc;
        const float* w1 = sW + (2 * k2 + 1) * OUT_C + oc;
        o0 = fmaf(hv.x, w0[0], o0); o1 = fmaf(hv.x, w0[1], o1);
        o0 = fmaf(hv.y, w1[0], o0); o1 = fmaf(hv.y, w1[1], o1);
    }
    *(__half2*)(gs + (size_t)node * OUT_C + oc) = __floats2half2_rn(o0 * dv, o1 * dv);
}

// ---- layer-2 aggregate: 8 lanes x float2 per node (8 nodes/wave), full 64 B rows,
//      same coalesced-col + shfl + prefetch structure, padded CSR. ----
__global__ void agg2_kernel(const int* __restrict__ ncur,
                            const int* __restrict__ col,
                            const float2* __restrict__ gsf,
                            const float* __restrict__ b2, float* __restrict__ out) {
    const int node = blockIdx.x * 32 + (threadIdx.x >> 3);   // grid 3125*32 == N exactly
    const int lane = threadIdx.x & 7;              // float2 index: channels 4*lane..4*lane+3
    const int cnt = min(ncur[node], CAP);
    const int beg = node << 6;
    const int end = beg + cnt;
    float2 u = gsf[(size_t)node * 8 + lane];       // self loop
    __half2* uh = (__half2*)&u;
    float2 t0 = __half22float2(uh[0]), t1 = __half22float2(uh[1]);
    float a0 = t0.x, a1 = t0.y, a2 = t1.x, a3 = t1.y;

    int j = beg;
    int idx0 = j + lane;
    int cv = (idx0 < end) ? col[idx0] : 0;
    while (j + 8 <= end) {
        int jn = j + 8;
        int idxn = jn + lane;
        int cvn = (idxn < end) ? col[idxn] : 0;    // prefetch next chunk
        int s[8];
#pragma unroll
        for (int e = 0; e < 8; ++e) s[e] = __shfl(cv, e, 8);
        float2 v[8];
#pragma unroll
        for (int e = 0; e < 8; ++e) v[e] = gsf[(size_t)s[e] * 8 + lane];
        cv = cvn;
#pragma unroll
        for (int e = 0; e < 8; ++e) {
            __half2* vh = (__half2*)&v[e];
            float2 w0 = __half22float2(vh[0]), w1 = __half22float2(vh[1]);
            a0 += w0.x; a1 += w0.y; a2 += w1.x; a3 += w1.y;
        }
        j = jn;
    }
    const int tail = end - j;
    for (int e = 0; e < tail; ++e) {
        int s = __shfl(cv, e, 8);
        float2 v = gsf[(size_t)s * 8 + lane];
        __half2* vh = (__half2*)&v;
        float2 w0 = __half22float2(vh[0]), w1 = __half22float2(vh[1]);
        a0 += w0.x; a1 += w0.y; a2 += w1.x; a3 += w1.y;
    }
    float dv = rsqrtf((float)cnt + 1.0f);
    float4 bb = ((const float4*)b2)[lane];
    float4 o;
    o.x = dv * a0 + bb.x;
    o.y = dv * a1 + bb.y;
    o.z = dv * a2 + bb.z;
    o.w = dv * a3 + bb.w;
    *(float4*)(out + (size_t)node * OUT_C + lane * 4) = o;
}

extern "C" void kernel_launch(void* const* d_in, const int* in_sizes, int n_in,
                              void* d_out, int out_size, void* d_ws, size_t ws_size,
                              hipStream_t stream) {
    const float* x  = (const float*)d_in[0];   // [N,128]
    const int*   ei = (const int*)d_in[1];     // [2,E]
    const float* W1 = (const float*)d_in[2];   // [128,64]
    const float* b1 = (const float*)d_in[3];   // [64]
    const float* W2 = (const float*)d_in[4];   // [64,32]
    const float* b2 = (const float*)d_in[5];   // [32]
    float* out = (float*)d_out;                // [N,32]

    const int* srcv = ei;
    const int* dstv = ei + E_EDGES;

    // workspace layout (~45 MB; ws is ~268 MB). gs is a DEDICATED region (agg1 reads
    // hs while writing gs -> must not alias).
    __half* hs   = (__half*)d_ws;                           // N*64 halves (12.8 MB)
    __half* gs   = hs + (size_t)N_NODES * HID_C;            // N*32 halves (6.4 MB)
    int* ncur    = (int*)(gs + (size_t)N_NODES * OUT_C);    // N ints (degree counters)
    int* colp    = ncur + N_NODES;                          // N*64 ints (padded CSR)

    // CSR build: direct padded per-node scatter (sort kernel deleted)
    zero_ncur_kernel<<<(N_NODES + 255) / 256, 256, 0, stream>>>(ncur);
    edge_scatter_kernel<<<E_EDGES / 256, 256, 0, stream>>>(srcv, dstv, ncur, colp);

    // layer 1 GEMM (64 rows/block, grid 1563)
    gemm1_kernel<<<(N_NODES + 63) / 64, 256, 0, stream>>>(x, W1, ncur, hs);

    // layer-1 aggregate + fused layer-2 GEMM
    agg1_kernel<<<N_NODES / 16, 256, 0, stream>>>(ncur, colp, (const float2*)hs,
                                                  b1, W2, gs);

    // layer-2 aggregate
    agg2_kernel<<<(N_NODES + 31) / 32, 256, 0, stream>>>(ncur, colp, (const float2*)gs,
                                                         b2, out);
}

// Round 10
// 136.032 us; speedup vs baseline: 1.5925x; 1.5925x over previous
//
#include <hip/hip_runtime.h>
#include <hip/hip_fp16.h>

#define N_NODES 100000
#define E_EDGES 1600000
#define IN_C 128
#define HID_C 64
#define OUT_C 32
#define BNODES 64                                   // nodes per bucket (dst>>6)
#define NBUCK ((N_NODES + BNODES - 1) / BNODES)     // 1563
#define MAXB 2048                                   // bucket cap (mean 1024, sigma~32)
#define NCHUNK 256                                  // edge chunks (privatized hist)
#define CHUNK_E (E_EDGES / NCHUNK)                  // 6250

// chunk<->block swizzle: consecutive chunks land on the same XCD (blockIdx%8 heuristic),
// so adjacent bucket windows (shared 64B lines) merge in one L2 instead of ping-ponging.
__device__ __forceinline__ int chunk_of_block(int b) { return (b & 7) * (NCHUNK / 8) + (b >> 3); }

// ---- zero the global bucket cursors (workspace is poisoned between iterations) ----
__global__ void zero_gcur_kernel(int* __restrict__ gcur) {
    int i = blockIdx.x * 256 + threadIdx.x;
    if (i < NBUCK) gcur[i] = 0;
}

// ---- single-pass bucketing: per-chunk LDS histogram -> atomic window reservation in
//      gcur -> scatter into PADDED per-bucket regions (b*MAXB). (Round-9 lesson:
//      direct per-node scatter = 134 us of random-line RMW; dense bucket windows
//      are what keep this at ~9 us.) ----
__global__ __launch_bounds__(1024) void bucket_scatter_kernel(const int* __restrict__ src,
                                                              const int* __restrict__ dst,
                                                              int* __restrict__ gcur,
                                                              unsigned* __restrict__ pairs) {
    __shared__ int h[NBUCK];                        // count -> base cursor (reused)
    for (int i = threadIdx.x; i < NBUCK; i += 1024) h[i] = 0;
    __syncthreads();
    const int chunk = chunk_of_block(blockIdx.x);
    const int base = chunk * CHUNK_E;
    int dc[7];                                      // ceil(6250/1024) = 7
    int nj = 0;
    for (int j = threadIdx.x; j < CHUNK_E; j += 1024) {
        int d = dst[base + j];
        dc[nj++] = d;
        atomicAdd(&h[d >> 6], 1);
    }
    __syncthreads();
    for (int i = threadIdx.x; i < NBUCK; i += 1024) {
        int c = h[i];
        if (c > 0) h[i] = atomicAdd(&gcur[i], c);   // reserve window; h becomes cursor
    }
    __syncthreads();
    nj = 0;
    for (int j = threadIdx.x; j < CHUNK_E; j += 1024) {
        int d = dc[nj++];
        int pos = atomicAdd(&h[d >> 6], 1);
        pairs[(unsigned)(d >> 6) * MAXB + (unsigned)pos] =
            ((unsigned)src[base + j] << 6) | (unsigned)(d & 63);
    }
}

// ---- per-bucket counting sort -> node-level padded CSR, in place (LDS stage). ----
__global__ __launch_bounds__(256) void bucket_sort_kernel(const int* __restrict__ gcur,
                                                          unsigned* __restrict__ pairs,
                                                          int* __restrict__ row_beg,
                                                          int* __restrict__ row_end,
                                                          float* __restrict__ dinv) {
    __shared__ unsigned sp[MAXB];
    __shared__ int hcnt[BNODES], scn[BNODES], cur[BNODES];
    const int b = blockIdx.x;
    const int beg = b * MAXB;
    int cnt = gcur[b];
    if (cnt > MAXB) cnt = MAXB;                     // safety clamp (cap is 32 sigma)
    if (threadIdx.x < BNODES) hcnt[threadIdx.x] = 0;
    __syncthreads();
    for (int j = threadIdx.x; j < cnt; j += 256) {
        unsigned p = pairs[beg + j];
        sp[j] = p;
        atomicAdd(&hcnt[p & 63], 1);
    }
    __syncthreads();
    if (threadIdx.x < BNODES) scn[threadIdx.x] = hcnt[threadIdx.x];
    __syncthreads();
    for (int off = 1; off < BNODES; off <<= 1) {
        int t = 0;
        if (threadIdx.x < BNODES && threadIdx.x >= off) t = scn[threadIdx.x - off];
        __syncthreads();
        if (threadIdx.x < BNODES) scn[threadIdx.x] += t;
        __syncthreads();
    }
    if (threadIdx.x < BNODES) {
        int ex = scn[threadIdx.x] - hcnt[threadIdx.x];   // exclusive
        cur[threadIdx.x] = ex;
        int node = b * BNODES + threadIdx.x;
        if (node < N_NODES) {
            row_beg[node] = beg + ex;
            row_end[node] = beg + ex + hcnt[threadIdx.x];
            dinv[node] = rsqrtf((float)hcnt[threadIdx.x] + 1.0f);
        }
    }
    __syncthreads();
    for (int j = threadIdx.x; j < cnt; j += 256) {
        unsigned p = sp[j];
        int pos = atomicAdd(&cur[p & 63], 1);
        pairs[beg + pos] = p >> 6;                      // now plain src index
    }
}

// ---- hs(fp16) = dinv[row] * (x @ W1), HALF-COLUMN blocks: 64 rows x 32 cols,
//      grid 3126 (2 col-halves), sW 16 KB -> LDS cap 10 blocks/CU (was 5 at 32 KB);
//      x read as 4 consecutive float4 (one full 64 B line) per batch, 16 k-steps of
//      FMA per batch. k order 0..127 ascending per output -> bit-identical hs. ----
__global__ __launch_bounds__(256) void gemm1_kernel(const float* __restrict__ x,
                                                    const float* __restrict__ W1,
                                                    const float* __restrict__ dinv,
                                                    __half* __restrict__ hs) {
    __shared__ float sW[IN_C * 32];                // 16 KB: W1 cols [half*32, half*32+32)
    const int half = blockIdx.x & 1;
    for (int i = threadIdx.x; i < IN_C * 32; i += 256) {
        int k = i >> 5, c = i & 31;
        sW[i] = W1[k * HID_C + half * 32 + c];
    }
    __syncthreads();
    const int cg = (threadIdx.x & 3) * 8;          // 8-col group within the half
    const int row = (blockIdx.x >> 1) * 64 + (threadIdx.x >> 2);
    const int rr = min(row, N_NODES - 1);
    float acc[8];
#pragma unroll
    for (int c = 0; c < 8; ++c) acc[c] = 0.f;

    const float4* x4 = (const float4*)x;
#pragma unroll 2
    for (int k16 = 0; k16 < IN_C / 16; ++k16) {    // 8 batches of 16 k
        float4 xq[4];                              // 64 B = one full line of this row
#pragma unroll
        for (int q = 0; q < 4; ++q) xq[q] = x4[(size_t)rr * (IN_C / 4) + k16 * 4 + q];
        float xs[16];
#pragma unroll
        for (int q = 0; q < 4; ++q) {
            xs[4 * q] = xq[q].x; xs[4 * q + 1] = xq[q].y;
            xs[4 * q + 2] = xq[q].z; xs[4 * q + 3] = xq[q].w;
        }
#pragma unroll
        for (int kk = 0; kk < 16; ++kk) {
            const float4* wp = (const float4*)(sW + (k16 * 16 + kk) * 32 + cg);
            float4 w0 = wp[0], w1 = wp[1];
            float wv[8] = {w0.x, w0.y, w0.z, w0.w, w1.x, w1.y, w1.z, w1.w};
#pragma unroll
            for (int c = 0; c < 8; ++c)
                acc[c] = fmaf(xs[kk], wv[c], acc[c]);
        }
    }
    if (row < N_NODES) {
        float dv = dinv[row];
        union { float4 f; __half2 h[4]; } u;
#pragma unroll
        for (int q = 0; q < 4; ++q)
            u.h[q] = __floats2half2_rn(acc[2 * q] * dv, acc[2 * q + 1] * dv);
        *(float4*)(hs + (size_t)row * HID_C + half * 32 + cg) = u.f;   // 16 B store
    }
}

// ---- layer-1 aggregate + FUSED gemm2 (round-4/7 proven form): 16 lanes x float2
//      per node (4 nodes/wave), full 128 B rows; col coalesced by 8 lanes + __shfl
//      broadcast + next-chunk prefetch. Epilogue: h2 row staged in 2 KB LDS tile;
//      gemm2 vs 8 KB LDS W2 copy, k ascending -> bit-identical gs.
//      gs must NOT alias hs. ----
__global__ __launch_bounds__(256) void agg1_kernel(const int* __restrict__ row_beg,
                                                   const int* __restrict__ row_end,
                                                   const int* __restrict__ col,
                                                   const float2* __restrict__ hsf,
                                                   const float* __restrict__ dinv,
                                                   const float* __restrict__ b1,
                                                   const float* __restrict__ W2,
                                                   __half* __restrict__ gs) {
    __shared__ float sW[HID_C * OUT_C];            // 8 KB W2 copy
    __shared__ __half2 sh2[16][HID_C / 2];         // 2 KB h2 tile (16 nodes x 64 ch)
    for (int i = threadIdx.x; i < HID_C * OUT_C; i += 256) sW[i] = W2[i];

    const int nl = threadIdx.x >> 4;               // node slot in block (0..15)
    const int node = blockIdx.x * 16 + nl;         // grid 6250 * 16 = exactly N
    const int lane = threadIdx.x & 15;             // float2 index: channels 4*lane..4*lane+3
    const int beg = row_beg[node], end = row_end[node];
    float2 u = hsf[(size_t)node * 16 + lane];      // self loop
    __half2* uh = (__half2*)&u;
    float2 t0 = __half22float2(uh[0]), t1 = __half22float2(uh[1]);
    float a0 = t0.x, a1 = t0.y, a2 = t1.x, a3 = t1.y;

    int j = beg;
    int idx0 = j + (lane & 7);
    int cv = (idx0 < end) ? col[idx0] : 0;         // current chunk's indices (coalesced)
    while (j + 8 <= end) {
        int jn = j + 8;
        int idxn = jn + (lane & 7);
        int cvn = (idxn < end) ? col[idxn] : 0;    // prefetch next chunk
        int s[8];
#pragma unroll
        for (int e = 0; e < 8; ++e) s[e] = __shfl(cv, e, 8);
        float2 v[8];
#pragma unroll
        for (int e = 0; e < 8; ++e) v[e] = hsf[(size_t)s[e] * 16 + lane];
        cv = cvn;
#pragma unroll
        for (int e = 0; e < 8; ++e) {
            __half2* vh = (__half2*)&v[e];
            float2 w0 = __half22float2(vh[0]), w1 = __half22float2(vh[1]);
            a0 += w0.x; a1 += w0.y; a2 += w1.x; a3 += w1.y;
        }
        j = jn;
    }
    const int tail = end - j;                      // 0..7, cv already holds tail indices
    for (int e = 0; e < tail; ++e) {
        int s = __shfl(cv, e, 8);
        float2 v = hsf[(size_t)s * 16 + lane];
        __half2* vh = (__half2*)&v;
        float2 w0 = __half22float2(vh[0]), w1 = __half22float2(vh[1]);
        a0 += w0.x; a1 += w0.y; a2 += w1.x; a3 += w1.y;
    }
    const float dv = dinv[node];
    float4 bb = ((const float4*)b1)[lane];
    __half2 p0 = __floats2half2_rn(fmaxf(dv * a0 + bb.x, 0.f), fmaxf(dv * a1 + bb.y, 0.f));
    __half2 p1 = __floats2half2_rn(fmaxf(dv * a2 + bb.z, 0.f), fmaxf(dv * a3 + bb.w, 0.f));
    sh2[nl][lane * 2] = p0;
    sh2[nl][lane * 2 + 1] = p1;
    __syncthreads();                               // covers sW and sh2

    // gemm2 phase: thread -> (node nl, out channels oc, oc+1); k order 0..63 sequential
    const int oc = lane * 2;
    float o0 = 0.f, o1 = 0.f;
#pragma unroll
    for (int k2 = 0; k2 < HID_C / 2; ++k2) {
        float2 hv = __half22float2(sh2[nl][k2]);
        const float* w0 = sW + (2 * k2) * OUT_C + oc;
        const float* w1 = sW + (2 * k2 + 1) * OUT_C + oc;
        o0 = fmaf(hv.x, w0[0], o0); o1 = fmaf(hv.x, w0[1], o1);
        o0 = fmaf(hv.y, w1[0], o0); o1 = fmaf(hv.y, w1[1], o1);
    }
    *(__half2*)(gs + (size_t)node * OUT_C + oc) = __floats2half2_rn(o0 * dv, o1 * dv);
}

// ---- layer-2 aggregate: 8 lanes x float2 per node (8 nodes/wave), full 64 B rows,
//      same coalesced-col + shfl + prefetch structure. ----
__global__ void agg2_kernel(const int* __restrict__ row_beg, const int* __restrict__ row_end,
                            const int* __restrict__ col,
                            const float2* __restrict__ gsf, const float* __restrict__ dinv,
                            const float* __restrict__ b2, float* __restrict__ out) {
    const int node = blockIdx.x * 32 + (threadIdx.x >> 3);
    const int lane = threadIdx.x & 7;              // float2 index: channels 4*lane..4*lane+3
    if (node >= N_NODES) return;
    const int beg = row_beg[node], end = row_end[node];
    float2 u = gsf[(size_t)node * 8 + lane];       // self loop
    __half2* uh = (__half2*)&u;
    float2 t0 = __half22float2(uh[0]), t1 = __half22float2(uh[1]);
    float a0 = t0.x, a1 = t0.y, a2 = t1.x, a3 = t1.y;

    int j = beg;
    int idx0 = j + lane;
    int cv = (idx0 < end) ? col[idx0] : 0;
    while (j + 8 <= end) {
        int jn = j + 8;
        int idxn = jn + lane;
        int cvn = (idxn < end) ? col[idxn] : 0;    // prefetch next chunk
        int s[8];
#pragma unroll
        for (int e = 0; e < 8; ++e) s[e] = __shfl(cv, e, 8);
        float2 v[8];
#pragma unroll
        for (int e = 0; e < 8; ++e) v[e] = gsf[(size_t)s[e] * 8 + lane];
        cv = cvn;
#pragma unroll
        for (int e = 0; e < 8; ++e) {
            __half2* vh = (__half2*)&v[e];
            float2 w0 = __half22float2(vh[0]), w1 = __half22float2(vh[1]);
            a0 += w0.x; a1 += w0.y; a2 += w1.x; a3 += w1.y;
        }
        j = jn;
    }
    const int tail = end - j;
    for (int e = 0; e < tail; ++e) {
        int s = __shfl(cv, e, 8);
        float2 v = gsf[(size_t)s * 8 + lane];
        __half2* vh = (__half2*)&v;
        float2 w0 = __half22float2(vh[0]), w1 = __half22float2(vh[1]);
        a0 += w0.x; a1 += w0.y; a2 += w1.x; a3 += w1.y;
    }
    float dv = dinv[node];
    float4 bb = ((const float4*)b2)[lane];
    float4 o;
    o.x = dv * a0 + bb.x;
    o.y = dv * a1 + bb.y;
    o.z = dv * a2 + bb.z;
    o.w = dv * a3 + bb.w;
    *(float4*)(out + (size_t)node * OUT_C + lane * 4) = o;
}

extern "C" void kernel_launch(void* const* d_in, const int* in_sizes, int n_in,
                              void* d_out, int out_size, void* d_ws, size_t ws_size,
                              hipStream_t stream) {
    const float* x  = (const float*)d_in[0];   // [N,128]
    const int*   ei = (const int*)d_in[1];     // [2,E]
    const float* W1 = (const float*)d_in[2];   // [128,64]
    const float* b1 = (const float*)d_in[3];   // [64]
    const float* W2 = (const float*)d_in[4];   // [64,32]
    const float* b2 = (const float*)d_in[5];   // [32]
    float* out = (float*)d_out;                // [N,32]

    const int* srcv = ei;
    const int* dstv = ei + E_EDGES;

    // workspace layout (~33 MB; ws is ~268 MB). gs is a DEDICATED region (agg1 reads
    // hs while writing gs -> must not alias).
    float* dinv  = (float*)d_ws;                            // N floats
    __half* hs   = (__half*)(dinv + N_NODES);               // N*64 halves
    __half* gs   = hs + (size_t)N_NODES * HID_C;            // N*32 halves
    int* row_beg = (int*)(gs + (size_t)N_NODES * OUT_C);    // N
    int* row_end = row_beg + N_NODES;                       // N
    int* gcur    = row_end + N_NODES;                       // NBUCK (pad to 1568)
    unsigned* pairs = (unsigned*)(gcur + 1568);             // NBUCK*MAXB (padded buckets)
    int* col = (int*)pairs;

    // CSR build: atomic bucket-window reservation
    zero_gcur_kernel<<<(NBUCK + 255) / 256, 256, 0, stream>>>(gcur);
    bucket_scatter_kernel<<<NCHUNK, 1024, 0, stream>>>(srcv, dstv, gcur, pairs);
    bucket_sort_kernel<<<NBUCK, 256, 0, stream>>>(gcur, pairs, row_beg, row_end, dinv);

    // layer 1 GEMM (64 rows x 32 cols per block, grid 3126)
    gemm1_kernel<<<2 * ((N_NODES + 63) / 64), 256, 0, stream>>>(x, W1, dinv, hs);

    // layer-1 aggregate + fused layer-2 GEMM
    agg1_kernel<<<N_NODES / 16, 256, 0, stream>>>(row_beg, row_end, col,
                                                  (const float2*)hs, dinv, b1, W2, gs);

    // layer-2 aggregate
    agg2_kernel<<<(N_NODES + 31) / 32, 256, 0, stream>>>(row_beg, row_end, col,
                                                         (const float2*)gs, dinv, b2, out);
}

// Round 11
// 126.025 us; speedup vs baseline: 1.7190x; 1.0794x over previous
//
#include <hip/hip_runtime.h>
#include <hip/hip_fp16.h>

#define N_NODES 100000
#define E_EDGES 1600000
#define IN_C 128
#define HID_C 64
#define OUT_C 32
#define BNODES 64                                   // nodes per bucket (dst>>6)
#define NBUCK ((N_NODES + BNODES - 1) / BNODES)     // 1563
#define MAXB 2048                                   // bucket cap (mean 1024, sigma~32)
#define NCHUNK 256                                  // edge chunks (privatized hist)
#define CHUNK_E (E_EDGES / NCHUNK)                  // 6250

// chunk<->block swizzle: consecutive chunks land on the same XCD (blockIdx%8 heuristic),
// so adjacent bucket windows (shared 64B lines) merge in one L2 instead of ping-ponging.
__device__ __forceinline__ int chunk_of_block(int b) { return (b & 7) * (NCHUNK / 8) + (b >> 3); }

// ---- zero the global bucket cursors (workspace is poisoned between iterations) ----
__global__ void zero_gcur_kernel(int* __restrict__ gcur) {
    int i = blockIdx.x * 256 + threadIdx.x;
    if (i < NBUCK) gcur[i] = 0;
}

// ---- single-pass bucketing: per-chunk LDS histogram -> atomic window reservation in
//      gcur -> scatter into PADDED per-bucket regions (b*MAXB). (Round-9 lesson:
//      direct per-node scatter = 134 us of random-line RMW; dense bucket windows
//      are what keep this at ~9 us.) ----
__global__ __launch_bounds__(1024) void bucket_scatter_kernel(const int* __restrict__ src,
                                                              const int* __restrict__ dst,
                                                              int* __restrict__ gcur,
                                                              unsigned* __restrict__ pairs) {
    __shared__ int h[NBUCK];                        // count -> base cursor (reused)
    for (int i = threadIdx.x; i < NBUCK; i += 1024) h[i] = 0;
    __syncthreads();
    const int chunk = chunk_of_block(blockIdx.x);
    const int base = chunk * CHUNK_E;
    int dc[7];                                      // ceil(6250/1024) = 7
    int nj = 0;
    for (int j = threadIdx.x; j < CHUNK_E; j += 1024) {
        int d = dst[base + j];
        dc[nj++] = d;
        atomicAdd(&h[d >> 6], 1);
    }
    __syncthreads();
    for (int i = threadIdx.x; i < NBUCK; i += 1024) {
        int c = h[i];
        if (c > 0) h[i] = atomicAdd(&gcur[i], c);   // reserve window; h becomes cursor
    }
    __syncthreads();
    nj = 0;
    for (int j = threadIdx.x; j < CHUNK_E; j += 1024) {
        int d = dc[nj++];
        int pos = atomicAdd(&h[d >> 6], 1);
        pairs[(unsigned)(d >> 6) * MAXB + (unsigned)pos] =
            ((unsigned)src[base + j] << 6) | (unsigned)(d & 63);
    }
}

// ---- per-bucket counting sort -> node-level padded CSR, in place (LDS stage). ----
__global__ __launch_bounds__(256) void bucket_sort_kernel(const int* __restrict__ gcur,
                                                          unsigned* __restrict__ pairs,
                                                          int* __restrict__ row_beg,
                                                          int* __restrict__ row_end,
                                                          float* __restrict__ dinv) {
    __shared__ unsigned sp[MAXB];
    __shared__ int hcnt[BNODES], scn[BNODES], cur[BNODES];
    const int b = blockIdx.x;
    const int beg = b * MAXB;
    int cnt = gcur[b];
    if (cnt > MAXB) cnt = MAXB;                     // safety clamp (cap is 32 sigma)
    if (threadIdx.x < BNODES) hcnt[threadIdx.x] = 0;
    __syncthreads();
    for (int j = threadIdx.x; j < cnt; j += 256) {
        unsigned p = pairs[beg + j];
        sp[j] = p;
        atomicAdd(&hcnt[p & 63], 1);
    }
    __syncthreads();
    if (threadIdx.x < BNODES) scn[threadIdx.x] = hcnt[threadIdx.x];
    __syncthreads();
    for (int off = 1; off < BNODES; off <<= 1) {
        int t = 0;
        if (threadIdx.x < BNODES && threadIdx.x >= off) t = scn[threadIdx.x - off];
        __syncthreads();
        if (threadIdx.x < BNODES) scn[threadIdx.x] += t;
        __syncthreads();
    }
    if (threadIdx.x < BNODES) {
        int ex = scn[threadIdx.x] - hcnt[threadIdx.x];   // exclusive
        cur[threadIdx.x] = ex;
        int node = b * BNODES + threadIdx.x;
        if (node < N_NODES) {
            row_beg[node] = beg + ex;
            row_end[node] = beg + ex + hcnt[threadIdx.x];
            dinv[node] = rsqrtf((float)hcnt[threadIdx.x] + 1.0f);
        }
    }
    __syncthreads();
    for (int j = threadIdx.x; j < cnt; j += 256) {
        unsigned p = sp[j];
        int pos = atomicAdd(&cur[p & 63], 1);
        pairs[beg + pos] = p >> 6;                      // now plain src index
    }
}

// ---- hs(fp16) = dinv[row] * (x @ W1), LDS-STAGED both operands per 32-k chunk:
//      128 rows/block (grid 782), 256 thr, 4 rows x 8 cols per thread.
//      xt[128][36] (pad 36 -> 16B-aligned b128, <=2-way banks) filled with
//      full-line coalesced loads (round-10 lesson: per-INSTRUCTION line coverage is
//      what the fabric charges; fragmented 16B/row requests ran at 1.26 TB/s).
//      sWc[32][64] staged per chunk (8 KB) -> LDS 26.6 KB -> 6 blocks/CU.
//      k ascending 0..127 -> bit-identical hs. ----
__global__ __launch_bounds__(256) void gemm1_kernel(const float* __restrict__ x,
                                                    const float* __restrict__ W1,
                                                    const float* __restrict__ dinv,
                                                    __half* __restrict__ hs) {
    __shared__ float xt[128 * 36];                 // 18 KB x tile, row stride 36 words
    __shared__ float sWc[32 * 64];                 // 8 KB W1 k-chunk
    const int row0 = blockIdx.x * 128;
    const int colg = (threadIdx.x & 7) * 8;        // 8 cols per thread
    const int rowg = (threadIdx.x >> 3) * 4;       // 4 rows per thread (32 row-groups)
    float acc[4][8];
#pragma unroll
    for (int r = 0; r < 4; ++r)
#pragma unroll
        for (int c = 0; c < 8; ++c) acc[r][c] = 0.f;

    const float4* x4 = (const float4*)x;
    const float4* w4 = (const float4*)W1;

    for (int c = 0; c < 4; ++c) {                  // k chunks of 32
        __syncthreads();                           // previous chunk's compute done
        // stage x chunk: 128 rows x 8 float4; per instr: 8 rows x 128 B contiguous
#pragma unroll
        for (int i = 0; i < 4; ++i) {
            int g = i * 256 + threadIdx.x;
            int r = g >> 3, k4 = g & 7;
            int rg = min(row0 + r, N_NODES - 1);
            float4 v = x4[(size_t)rg * (IN_C / 4) + c * 8 + k4];
            *(float4*)(xt + r * 36 + k4 * 4) = v;
        }
        // stage W chunk: rows c*32..c*32+31, all 64 cols; fully coalesced
#pragma unroll
        for (int i = 0; i < 2; ++i) {
            int f = i * 256 + threadIdx.x;         // float4 index in [0,512)
            int wr = f >> 4, wc4 = f & 15;
            *(float4*)(sWc + wr * 64 + wc4 * 4) = w4[(size_t)(c * 32 + wr) * 16 + wc4];
        }
        __syncthreads();
        // compute 32 k, ascending
#pragma unroll
        for (int k4 = 0; k4 < 8; ++k4) {
            float4 xr[4];
#pragma unroll
            for (int ri = 0; ri < 4; ++ri)
                xr[ri] = *(const float4*)(xt + (rowg + ri) * 36 + k4 * 4);
#pragma unroll
            for (int j = 0; j < 4; ++j) {
                const float4* wp = (const float4*)(sWc + (k4 * 4 + j) * 64 + colg);
                float4 w0 = wp[0], w1 = wp[1];
                float wv[8] = {w0.x, w0.y, w0.z, w0.w, w1.x, w1.y, w1.z, w1.w};
#pragma unroll
                for (int ri = 0; ri < 4; ++ri) {
                    const float* xf = (const float*)&xr[ri];
                    float xs = xf[j];
#pragma unroll
                    for (int cc = 0; cc < 8; ++cc)
                        acc[ri][cc] = fmaf(xs, wv[cc], acc[ri][cc]);
                }
            }
        }
    }
#pragma unroll
    for (int ri = 0; ri < 4; ++ri) {
        int row = row0 + rowg + ri;
        if (row < N_NODES) {
            float dv = dinv[row];
            union { float4 f; __half2 h[4]; } u;
#pragma unroll
            for (int q = 0; q < 4; ++q)
                u.h[q] = __floats2half2_rn(acc[ri][2 * q] * dv, acc[ri][2 * q + 1] * dv);
            *(float4*)(hs + (size_t)row * HID_C + colg) = u.f;   // 16 B packed store
        }
    }
}

// ---- layer-1 aggregate + FUSED gemm2 (round-4/7 proven form, 42.2 us): 16 lanes x
//      float2 per node (4 nodes/wave), full 128 B rows; col coalesced by 8 lanes +
//      __shfl broadcast + next-chunk prefetch. Epilogue: h2 row staged in 2 KB LDS
//      tile; gemm2 vs 8 KB LDS W2 copy, k ascending -> bit-identical gs.
//      gs must NOT alias hs. ----
__global__ __launch_bounds__(256) void agg1_kernel(const int* __restrict__ row_beg,
                                                   const int* __restrict__ row_end,
                                                   const int* __restrict__ col,
                                                   const float2* __restrict__ hsf,
                                                   const float* __restrict__ dinv,
                                                   const float* __restrict__ b1,
                                                   const float* __restrict__ W2,
                                                   __half* __restrict__ gs) {
    __shared__ float sW[HID_C * OUT_C];            // 8 KB W2 copy
    __shared__ __half2 sh2[16][HID_C / 2];         // 2 KB h2 tile (16 nodes x 64 ch)
    for (int i = threadIdx.x; i < HID_C * OUT_C; i += 256) sW[i] = W2[i];

    const int nl = threadIdx.x >> 4;               // node slot in block (0..15)
    const int node = blockIdx.x * 16 + nl;         // grid 6250 * 16 = exactly N
    const int lane = threadIdx.x & 15;             // float2 index: channels 4*lane..4*lane+3
    const int beg = row_beg[node], end = row_end[node];
    float2 u = hsf[(size_t)node * 16 + lane];      // self loop
    __half2* uh = (__half2*)&u;
    float2 t0 = __half22float2(uh[0]), t1 = __half22float2(uh[1]);
    float a0 = t0.x, a1 = t0.y, a2 = t1.x, a3 = t1.y;

    int j = beg;
    int idx0 = j + (lane & 7);
    int cv = (idx0 < end) ? col[idx0] : 0;         // current chunk's indices (coalesced)
    while (j + 8 <= end) {
        int jn = j + 8;
        int idxn = jn + (lane & 7);
        int cvn = (idxn < end) ? col[idxn] : 0;    // prefetch next chunk
        int s[8];
#pragma unroll
        for (int e = 0; e < 8; ++e) s[e] = __shfl(cv, e, 8);
        float2 v[8];
#pragma unroll
        for (int e = 0; e < 8; ++e) v[e] = hsf[(size_t)s[e] * 16 + lane];
        cv = cvn;
#pragma unroll
        for (int e = 0; e < 8; ++e) {
            __half2* vh = (__half2*)&v[e];
            float2 w0 = __half22float2(vh[0]), w1 = __half22float2(vh[1]);
            a0 += w0.x; a1 += w0.y; a2 += w1.x; a3 += w1.y;
        }
        j = jn;
    }
    const int tail = end - j;                      // 0..7, cv already holds tail indices
    for (int e = 0; e < tail; ++e) {
        int s = __shfl(cv, e, 8);
        float2 v = hsf[(size_t)s * 16 + lane];
        __half2* vh = (__half2*)&v;
        float2 w0 = __half22float2(vh[0]), w1 = __half22float2(vh[1]);
        a0 += w0.x; a1 += w0.y; a2 += w1.x; a3 += w1.y;
    }
    const float dv = dinv[node];
    float4 bb = ((const float4*)b1)[lane];
    __half2 p0 = __floats2half2_rn(fmaxf(dv * a0 + bb.x, 0.f), fmaxf(dv * a1 + bb.y, 0.f));
    __half2 p1 = __floats2half2_rn(fmaxf(dv * a2 + bb.z, 0.f), fmaxf(dv * a3 + bb.w, 0.f));
    sh2[nl][lane * 2] = p0;
    sh2[nl][lane * 2 + 1] = p1;
    __syncthreads();                               // covers sW and sh2

    // gemm2 phase: thread -> (node nl, out channels oc, oc+1); k order 0..63 sequential
    const int oc = lane * 2;
    float o0 = 0.f, o1 = 0.f;
#pragma unroll
    for (int k2 = 0; k2 < HID_C / 2; ++k2) {
        float2 hv = __half22float2(sh2[nl][k2]);
        const float* w0 = sW + (2 * k2) * OUT_C + oc;
        const float* w1 = sW + (2 * k2 + 1) * OUT_C + oc;
        o0 = fmaf(hv.x, w0[0], o0); o1 = fmaf(hv.x, w0[1], o1);
        o0 = fmaf(hv.y, w1[0], o0); o1 = fmaf(hv.y, w1[1], o1);
    }
    *(__half2*)(gs + (size_t)node * OUT_C + oc) = __floats2half2_rn(o0 * dv, o1 * dv);
}

// ---- layer-2 aggregate: 8 lanes x float2 per node (8 nodes/wave), full 64 B rows,
//      same coalesced-col + shfl + prefetch structure. ----
__global__ void agg2_kernel(const int* __restrict__ row_beg, const int* __restrict__ row_end,
                            const int* __restrict__ col,
                            const float2* __restrict__ gsf, const float* __restrict__ dinv,
                            const float* __restrict__ b2, float* __restrict__ out) {
    const int node = blockIdx.x * 32 + (threadIdx.x >> 3);
    const int lane = threadIdx.x & 7;              // float2 index: channels 4*lane..4*lane+3
    if (node >= N_NODES) return;
    const int beg = row_beg[node], end = row_end[node];
    float2 u = gsf[(size_t)node * 8 + lane];       // self loop
    __half2* uh = (__half2*)&u;
    float2 t0 = __half22float2(uh[0]), t1 = __half22float2(uh[1]);
    float a0 = t0.x, a1 = t0.y, a2 = t1.x, a3 = t1.y;

    int j = beg;
    int idx0 = j + lane;
    int cv = (idx0 < end) ? col[idx0] : 0;
    while (j + 8 <= end) {
        int jn = j + 8;
        int idxn = jn + lane;
        int cvn = (idxn < end) ? col[idxn] : 0;    // prefetch next chunk
        int s[8];
#pragma unroll
        for (int e = 0; e < 8; ++e) s[e] = __shfl(cv, e, 8);
        float2 v[8];
#pragma unroll
        for (int e = 0; e < 8; ++e) v[e] = gsf[(size_t)s[e] * 8 + lane];
        cv = cvn;
#pragma unroll
        for (int e = 0; e < 8; ++e) {
            __half2* vh = (__half2*)&v[e];
            float2 w0 = __half22float2(vh[0]), w1 = __half22float2(vh[1]);
            a0 += w0.x; a1 += w0.y; a2 += w1.x; a3 += w1.y;
        }
        j = jn;
    }
    const int tail = end - j;
    for (int e = 0; e < tail; ++e) {
        int s = __shfl(cv, e, 8);
        float2 v = gsf[(size_t)s * 8 + lane];
        __half2* vh = (__half2*)&v;
        float2 w0 = __half22float2(vh[0]), w1 = __half22float2(vh[1]);
        a0 += w0.x; a1 += w0.y; a2 += w1.x; a3 += w1.y;
    }
    float dv = dinv[node];
    float4 bb = ((const float4*)b2)[lane];
    float4 o;
    o.x = dv * a0 + bb.x;
    o.y = dv * a1 + bb.y;
    o.z = dv * a2 + bb.z;
    o.w = dv * a3 + bb.w;
    *(float4*)(out + (size_t)node * OUT_C + lane * 4) = o;
}

extern "C" void kernel_launch(void* const* d_in, const int* in_sizes, int n_in,
                              void* d_out, int out_size, void* d_ws, size_t ws_size,
                              hipStream_t stream) {
    const float* x  = (const float*)d_in[0];   // [N,128]
    const int*   ei = (const int*)d_in[1];     // [2,E]
    const float* W1 = (const float*)d_in[2];   // [128,64]
    const float* b1 = (const float*)d_in[3];   // [64]
    const float* W2 = (const float*)d_in[4];   // [64,32]
    const float* b2 = (const float*)d_in[5];   // [32]
    float* out = (float*)d_out;                // [N,32]

    const int* srcv = ei;
    const int* dstv = ei + E_EDGES;

    // workspace layout (~33 MB; ws is ~268 MB). gs is a DEDICATED region (agg1 reads
    // hs while writing gs -> must not alias).
    float* dinv  = (float*)d_ws;                            // N floats
    __half* hs   = (__half*)(dinv + N_NODES);               // N*64 halves
    __half* gs   = hs + (size_t)N_NODES * HID_C;            // N*32 halves
    int* row_beg = (int*)(gs + (size_t)N_NODES * OUT_C);    // N
    int* row_end = row_beg + N_NODES;                       // N
    int* gcur    = row_end + N_NODES;                       // NBUCK (pad to 1568)
    unsigned* pairs = (unsigned*)(gcur + 1568);             // NBUCK*MAXB (padded buckets)
    int* col = (int*)pairs;

    // CSR build: atomic bucket-window reservation
    zero_gcur_kernel<<<(NBUCK + 255) / 256, 256, 0, stream>>>(gcur);
    bucket_scatter_kernel<<<NCHUNK, 1024, 0, stream>>>(srcv, dstv, gcur, pairs);
    bucket_sort_kernel<<<NBUCK, 256, 0, stream>>>(gcur, pairs, row_beg, row_end, dinv);

    // layer 1 GEMM (128 rows/block, two-tile LDS staging, grid 782)
    gemm1_kernel<<<(N_NODES + 127) / 128, 256, 0, stream>>>(x, W1, dinv, hs);

    // layer-1 aggregate + fused layer-2 GEMM
    agg1_kernel<<<N_NODES / 16, 256, 0, stream>>>(row_beg, row_end, col,
                                                  (const float2*)hs, dinv, b1, W2, gs);

    // layer-2 aggregate
    agg2_kernel<<<(N_NODES + 31) / 32, 256, 0, stream>>>(row_beg, row_end, col,
                                                         (const float2*)gs, dinv, b2, out);
}